// Round 4
// baseline (118.027 us; speedup 1.0000x reference)
//
#include <hip/hip_runtime.h>
#include <hip/hip_bf16.h>

#define SLEN 8192
#define EDIM 1024
#define NB   1024   // attention blocks; 8 positions per block (one per wave)

// ---------------- helpers ----------------

__device__ inline float waveReduceSum64(float v) {
#pragma unroll
    for (int off = 32; off; off >>= 1) v += __shfl_xor(v, off);
    return v;
}

__device__ inline float blockSum1024(float v, float* lds) {
    v = waveReduceSum64(v);
    int w = threadIdx.x >> 6, ln = threadIdx.x & 63;
    __syncthreads();
    if (ln == 0) lds[w] = v;
    __syncthreads();
    float s = (ln < 16) ? lds[ln] : 0.f;
#pragma unroll
    for (int off = 8; off; off >>= 1) s += __shfl_xor(s, off);
    s = __shfl(s, 0);
    return s;
}

// ---------------- QKV GEMV (split-K partials) ----------------
// grid (12, 16), block 256
__global__ __launch_bounds__(256) void qkv_partial(
    const float* __restrict__ Wq, const float* __restrict__ Wk,
    const float* __restrict__ Wv, const float* __restrict__ x,
    float* __restrict__ part) {
    int cg = blockIdx.x;
    int m = cg >> 2;
    const float* W = (m == 0) ? Wq : ((m == 1) ? Wk : Wv);
    int col = (cg & 3) * 256 + threadIdx.x;
    int r0 = blockIdx.y * 64;
    float acc = 0.f;
#pragma unroll 8
    for (int r = 0; r < 64; ++r)
        acc = fmaf(x[r0 + r], W[(r0 + r) * EDIM + col], acc);
    part[((size_t)m * 16 + blockIdx.y) * EDIM + col] = acc;
}

// grid 3, block 1024
__global__ __launch_bounds__(1024) void qkv_combine(
    const float* __restrict__ part,
    const float* __restrict__ bq, const float* __restrict__ bk,
    const float* __restrict__ bv,
    float* __restrict__ qs, float* __restrict__ ki, float* __restrict__ vi) {
    int m = blockIdx.x, t = threadIdx.x;
    float v = 0.f;
#pragma unroll
    for (int sl = 0; sl < 16; ++sl) v += part[((size_t)m * 16 + sl) * EDIM + t];
    if (m == 0) qs[t] = (v + bq[t]) * 0.125f;   // pre-scale q by 1/sqrt(64)
    else if (m == 1) ki[t] = v + bk[t];
    else vi[t] = v + bv[t];
}

// ---------------- fused cache-shift + attention with block merge ----------------
// grid NB, block 512 (8 waves). Wave w owns position s = blockIdx.x*8 + w.
// Block emits ONE softmax partial (m2,l2,acc2) per head.
__global__ __launch_bounds__(512) void attn_main(
    const float* __restrict__ cache,   // [2, S, 1024]
    const float* __restrict__ qs,      // q/8 [1024]
    const float* __restrict__ ki, const float* __restrict__ vi,
    float* __restrict__ nv, float* __restrict__ nk,
    float* __restrict__ m2, float* __restrict__ l2, float* __restrict__ acc2) {
    __shared__ float sm[8][16];        // per-wave per-head scores
    __shared__ float mlM[16], mlL[16];
    __shared__ float sacc[8][16][64];  // 32 KB weighted V
    int tid = threadIdx.x;
    int w = tid >> 6, ld = tid & 63;
    int s = blockIdx.x * 8 + w;

    const float* vsrc;
    const float* ksrc;
    if (s < SLEN - 1) {
        vsrc = cache + (size_t)(s + 1) * EDIM;
        ksrc = cache + (size_t)(SLEN + s + 1) * EDIM;
    } else {
        vsrc = vi; ksrc = ki;
    }

    // load V row, store to new cache, nz test
    float4 vv[4];
    bool nz = false;
#pragma unroll
    for (int it = 0; it < 4; ++it) {
        vv[it] = *(const float4*)(vsrc + it * 256 + ld * 4);
        *(float4*)(nv + (size_t)s * EDIM + it * 256 + ld * 4) = vv[it];
        nz = nz || (vv[it].x != 0.f) || (vv[it].y != 0.f) ||
             (vv[it].z != 0.f) || (vv[it].w != 0.f);
    }
    // K row: copy + per-head dot with q (16-lane-group reduce)
    float sc[4];
#pragma unroll
    for (int it = 0; it < 4; ++it) {
        float4 kv = *(const float4*)(ksrc + it * 256 + ld * 4);
        float4 q4 = *(const float4*)(qs + it * 256 + ld * 4);
        *(float4*)(nk + (size_t)s * EDIM + it * 256 + ld * 4) = kv;
        float d = q4.x * kv.x + q4.y * kv.y + q4.z * kv.z + q4.w * kv.w;
        d += __shfl_xor(d, 1);
        d += __shfl_xor(d, 2);
        d += __shfl_xor(d, 4);
        d += __shfl_xor(d, 8);
        sc[it] = d;    // score for head it*4 + (ld>>4)
    }
    if (__ballot(nz) == 0ull) {
#pragma unroll
        for (int it = 0; it < 4; ++it) sc[it] = -1e30f;
    }
    if ((ld & 15) == 0) {
#pragma unroll
        for (int it = 0; it < 4; ++it) sm[w][it * 4 + (ld >> 4)] = sc[it];
    }
    __syncthreads();

    // per-head block max / partition sum; write weighted V to LDS
#pragma unroll
    for (int it = 0; it < 4; ++it) {
        int h = it * 4 + (ld >> 4);
        float M = sm[0][h];
#pragma unroll
        for (int ww = 1; ww < 8; ++ww) M = fmaxf(M, sm[ww][h]);
        float L = 0.f;
#pragma unroll
        for (int ww = 0; ww < 8; ++ww) L += __expf(sm[ww][h] - M);
        if ((ld & 15) == 1) { mlM[h] = M; mlL[h] = L; }
        float wg = __expf(sc[it] - M);   // 0 for masked rows (v==0 anyway)
        *(float4*)&sacc[w][h][(ld & 15) * 4] =
            make_float4(wg * vv[it].x, wg * vv[it].y, wg * vv[it].z, wg * vv[it].w);
    }
    __syncthreads();

    // wave w reduces heads 2w, 2w+1 over the 8 waves; write block partial
#pragma unroll
    for (int j = 0; j < 2; ++j) {
        int h = 2 * w + j;
        float a = 0.f;
#pragma unroll
        for (int ww = 0; ww < 8; ++ww) a += sacc[ww][h][ld];
        acc2[((size_t)blockIdx.x * 16 + h) * 64 + ld] = a;
        if (ld == 0) {
            m2[blockIdx.x * 16 + h] = mlM[h];
            l2[blockIdx.x * 16 + h] = mlL[h];
        }
    }
}

// Wo GEMV with fused final attention reduce.
// grid (4, 16), block 256 (4 waves). blockIdx.y = head.
__global__ __launch_bounds__(256) void gemv_wo(
    const float* __restrict__ Wo,
    const float* __restrict__ m2, const float* __restrict__ l2,
    const float* __restrict__ acc2, float* __restrict__ part) {
    __shared__ float sM[4], sL[4], sA[4][64], vals[64];
    int by = blockIdx.y;
    int t = threadIdx.x;
    int w = t >> 6, ld = t & 63;
    int b0 = w * (NB / 4);
    float lm = -1e30f;
#pragma unroll 8
    for (int i = 0; i < NB / 4; ++i)
        lm = fmaxf(lm, m2[(b0 + i) * 16 + by]);
    float ll = 0.f, la = 0.f;
#pragma unroll 4
    for (int i = 0; i < NB / 4; ++i) {
        float e = __expf(m2[(b0 + i) * 16 + by] - lm);
        ll += e * l2[(b0 + i) * 16 + by];
        la += e * acc2[((size_t)(b0 + i) * 16 + by) * 64 + ld];
    }
    if (ld == 0) { sM[w] = lm; sL[w] = ll; }
    sA[w][ld] = la;
    __syncthreads();
    if (t < 64) {
        float M = fmaxf(fmaxf(sM[0], sM[1]), fmaxf(sM[2], sM[3]));
        float L = 0.f, a = 0.f;
#pragma unroll
        for (int w4 = 0; w4 < 4; ++w4) {
            float e = __expf(sM[w4] - M);
            L += e * sL[w4];
            a += e * sA[w4][t];
        }
        vals[t] = a / L;
    }
    __syncthreads();
    int col = blockIdx.x * 256 + t;
    float acc = 0.f;
#pragma unroll 8
    for (int r = 0; r < 64; ++r)
        acc = fmaf(vals[r], Wo[(size_t)(by * 64 + r) * EDIM + col], acc);
    part[(size_t)by * EDIM + col] = acc;
}

// generic GEMV partial: grid (4,16), block 256
__global__ __launch_bounds__(256) void gemv_partial(
    const float* __restrict__ W, const float* __restrict__ xin,
    float* __restrict__ part) {
    int col = blockIdx.x * 256 + threadIdx.x;
    int r0 = blockIdx.y * 64;
    float acc = 0.f;
#pragma unroll 8
    for (int r = 0; r < 64; ++r)
        acc = fmaf(xin[r0 + r], W[(size_t)(r0 + r) * EDIM + col], acc);
    part[(size_t)blockIdx.y * EDIM + col] = acc;
}

// W2 GEMV with fused (bias + sum-partials + ReLU) prologue for its row slice.
__global__ __launch_bounds__(256) void gemv_w2(
    const float* __restrict__ W2, const float* __restrict__ gp2,
    const float* __restrict__ b1, float* __restrict__ part) {
    __shared__ float vals[64];
    int by = blockIdx.y;
    int t = threadIdx.x;
    if (t < 64) {
        int r = by * 64 + t;
        float v = b1[r];
#pragma unroll
        for (int sl = 0; sl < 16; ++sl) v += gp2[(size_t)sl * EDIM + r];
        vals[t] = fmaxf(v, 0.f);
    }
    __syncthreads();
    int col = blockIdx.x * 256 + t;
    float acc = 0.f;
#pragma unroll 8
    for (int r = 0; r < 64; ++r)
        acc = fmaf(vals[r], W2[(size_t)(by * 64 + r) * EDIM + col], acc);
    part[(size_t)by * EDIM + col] = acc;
}

// 1 block 1024: r = resid + bias + sum partials; out = LN(r)*g + b
__global__ __launch_bounds__(1024) void combine_ln(
    const float* __restrict__ part, const float* __restrict__ bias,
    const float* __restrict__ resid, const float* __restrict__ g,
    const float* __restrict__ b, float* __restrict__ out) {
    __shared__ float lds[32];
    int t = threadIdx.x;
    float v = bias[t];
#pragma unroll
    for (int sl = 0; sl < 16; ++sl) v += part[(size_t)sl * EDIM + t];
    float r = resid[t] + v;
    float mean = blockSum1024(r, lds) * (1.f / 1024.f);
    float d = r - mean;
    float var = blockSum1024(d * d, lds) * (1.f / 1024.f);
    out[t] = d * rsqrtf(var + 1e-6f) * g[t] + b[t];
}

// ---------------- launch ----------------
extern "C" void kernel_launch(void* const* d_in, const int* in_sizes, int n_in,
                              void* d_out, int out_size, void* d_ws, size_t ws_size,
                              hipStream_t stream) {
    const float* x     = (const float*)d_in[0];
    const float* cache = (const float*)d_in[1];
    const float* Wv    = (const float*)d_in[2];
    const float* bv    = (const float*)d_in[3];
    const float* Wq    = (const float*)d_in[4];
    const float* bq    = (const float*)d_in[5];
    const float* Wk    = (const float*)d_in[6];
    const float* bk    = (const float*)d_in[7];
    const float* Wo    = (const float*)d_in[8];
    const float* bo    = (const float*)d_in[9];
    const float* W1    = (const float*)d_in[10];
    const float* b1    = (const float*)d_in[11];
    const float* W2    = (const float*)d_in[12];
    const float* b2    = (const float*)d_in[13];
    const float* ln1s  = (const float*)d_in[14];
    const float* ln1b  = (const float*)d_in[15];
    const float* ln2s  = (const float*)d_in[16];
    const float* ln2b  = (const float*)d_in[17];

    float* out = (float*)d_out;
    float* nv = out + 1024;
    float* nk = out + 1024 + (size_t)SLEN * EDIM;

    float* w      = (float*)d_ws;
    float* qs     = w;                          // 1024
    float* ki     = qs + 1024;                  // 1024
    float* vi     = ki + 1024;                  // 1024
    float* qkvp   = vi + 1024;                  // 48*1024
    float* m2     = qkvp + 48 * 1024;           // NB*16
    float* l2     = m2 + (size_t)NB * 16;       // NB*16
    float* acc2   = l2 + (size_t)NB * 16;       // NB*1024
    float* h1     = acc2 + (size_t)NB * 1024;   // 1024
    float* gp1    = h1 + 1024;                  // 16*1024
    float* gp2    = gp1 + 16 * 1024;            // 16*1024
    float* gp3    = gp2 + 16 * 1024;            // 16*1024

    qkv_partial<<<dim3(12, 16), 256, 0, stream>>>(Wq, Wk, Wv, x, qkvp);
    qkv_combine<<<3, 1024, 0, stream>>>(qkvp, bq, bk, bv, qs, ki, vi);
    attn_main<<<NB, 512, 0, stream>>>(cache, qs, ki, vi, nv, nk, m2, l2, acc2);
    gemv_wo<<<dim3(4, 16), 256, 0, stream>>>(Wo, m2, l2, acc2, gp1);
    combine_ln<<<1, 1024, 0, stream>>>(gp1, bo, x, ln1s, ln1b, h1);
    gemv_partial<<<dim3(4, 16), 256, 0, stream>>>(W1, h1, gp2);
    gemv_w2<<<dim3(4, 16), 256, 0, stream>>>(W2, gp2, b1, gp3);
    combine_ln<<<1, 1024, 0, stream>>>(gp3, b2, h1, ln2s, ln2b, out);
}

// Round 5
// 62.839 us; speedup vs baseline: 1.8783x; 1.8783x over previous
//
#include <hip/hip_runtime.h>
#include <hip/hip_bf16.h>

#define SLEN 8192
#define EDIM 1024
#define NB   1024   // attention blocks; 8 positions per block (one per wave)

// ---------------- helpers ----------------

__device__ inline float waveReduceSum64(float v) {
#pragma unroll
    for (int off = 32; off; off >>= 1) v += __shfl_xor(v, off);
    return v;
}

__device__ inline float blockSum1024(float v, float* lds) {
    v = waveReduceSum64(v);
    int w = threadIdx.x >> 6, ln = threadIdx.x & 63;
    __syncthreads();
    if (ln == 0) lds[w] = v;
    __syncthreads();
    float s = (ln < 16) ? lds[ln] : 0.f;
#pragma unroll
    for (int off = 8; off; off >>= 1) s += __shfl_xor(s, off);
    s = __shfl(s, 0);
    return s;
}

// ---------------- QKV GEMV (split-K partials) ----------------
// grid (12, 16), block 256
__global__ __launch_bounds__(256) void qkv_partial(
    const float* __restrict__ Wq, const float* __restrict__ Wk,
    const float* __restrict__ Wv, const float* __restrict__ x,
    float* __restrict__ part) {
    int cg = blockIdx.x;
    int m = cg >> 2;
    const float* W = (m == 0) ? Wq : ((m == 1) ? Wk : Wv);
    int col = (cg & 3) * 256 + threadIdx.x;
    int r0 = blockIdx.y * 64;
    float acc = 0.f;
#pragma unroll 8
    for (int r = 0; r < 64; ++r)
        acc = fmaf(x[r0 + r], W[(r0 + r) * EDIM + col], acc);
    part[((size_t)m * 16 + blockIdx.y) * EDIM + col] = acc;
}

// grid 3, block 1024
__global__ __launch_bounds__(1024) void qkv_combine(
    const float* __restrict__ part,
    const float* __restrict__ bq, const float* __restrict__ bk,
    const float* __restrict__ bv,
    float* __restrict__ qs, float* __restrict__ ki, float* __restrict__ vi) {
    int m = blockIdx.x, t = threadIdx.x;
    float v = 0.f;
#pragma unroll
    for (int sl = 0; sl < 16; ++sl) v += part[((size_t)m * 16 + sl) * EDIM + t];
    if (m == 0) qs[t] = (v + bq[t]) * 0.125f;   // pre-scale q by 1/sqrt(64)
    else if (m == 1) ki[t] = v + bk[t];
    else vi[t] = v + bv[t];
}

// ---------------- fused cache-shift + attention with block merge ----------------
// grid NB, block 512 (8 waves). Wave w owns position s = blockIdx.x*8 + w.
__global__ __launch_bounds__(512) void attn_main(
    const float* __restrict__ cache,   // [2, S, 1024]
    const float* __restrict__ qs,      // q/8 [1024]
    const float* __restrict__ ki, const float* __restrict__ vi,
    float* __restrict__ nv, float* __restrict__ nk,
    float* __restrict__ m2, float* __restrict__ l2, float* __restrict__ acc2) {
    __shared__ float sm[8][16];        // per-wave per-head scores
    __shared__ float mlM[16], mlL[16];
    __shared__ float sacc[8][16][64];  // 32 KB weighted V
    int tid = threadIdx.x;
    int w = tid >> 6, ld = tid & 63;
    int s = blockIdx.x * 8 + w;

    const float* vsrc;
    const float* ksrc;
    if (s < SLEN - 1) {
        vsrc = cache + (size_t)(s + 1) * EDIM;
        ksrc = cache + (size_t)(SLEN + s + 1) * EDIM;
    } else {
        vsrc = vi; ksrc = ki;
    }

    float4 vv[4];
    bool nz = false;
#pragma unroll
    for (int it = 0; it < 4; ++it) {
        vv[it] = *(const float4*)(vsrc + it * 256 + ld * 4);
        *(float4*)(nv + (size_t)s * EDIM + it * 256 + ld * 4) = vv[it];
        nz = nz || (vv[it].x != 0.f) || (vv[it].y != 0.f) ||
             (vv[it].z != 0.f) || (vv[it].w != 0.f);
    }
    float sc[4];
#pragma unroll
    for (int it = 0; it < 4; ++it) {
        float4 kv = *(const float4*)(ksrc + it * 256 + ld * 4);
        float4 q4 = *(const float4*)(qs + it * 256 + ld * 4);
        *(float4*)(nk + (size_t)s * EDIM + it * 256 + ld * 4) = kv;
        float d = q4.x * kv.x + q4.y * kv.y + q4.z * kv.z + q4.w * kv.w;
        d += __shfl_xor(d, 1);
        d += __shfl_xor(d, 2);
        d += __shfl_xor(d, 4);
        d += __shfl_xor(d, 8);
        sc[it] = d;    // score for head it*4 + (ld>>4)
    }
    if (__ballot(nz) == 0ull) {
#pragma unroll
        for (int it = 0; it < 4; ++it) sc[it] = -1e30f;
    }
    if ((ld & 15) == 0) {
#pragma unroll
        for (int it = 0; it < 4; ++it) sm[w][it * 4 + (ld >> 4)] = sc[it];
    }
    __syncthreads();

#pragma unroll
    for (int it = 0; it < 4; ++it) {
        int h = it * 4 + (ld >> 4);
        float M = sm[0][h];
#pragma unroll
        for (int ww = 1; ww < 8; ++ww) M = fmaxf(M, sm[ww][h]);
        float L = 0.f;
#pragma unroll
        for (int ww = 0; ww < 8; ++ww) L += __expf(sm[ww][h] - M);
        if ((ld & 15) == 1) { mlM[h] = M; mlL[h] = L; }
        float wg = __expf(sc[it] - M);
        *(float4*)&sacc[w][h][(ld & 15) * 4] =
            make_float4(wg * vv[it].x, wg * vv[it].y, wg * vv[it].z, wg * vv[it].w);
    }
    __syncthreads();

#pragma unroll
    for (int j = 0; j < 2; ++j) {
        int h = 2 * w + j;
        float a = 0.f;
#pragma unroll
        for (int ww = 0; ww < 8; ++ww) a += sacc[ww][h][ld];
        acc2[((size_t)blockIdx.x * 16 + h) * 64 + ld] = a;
        if (ld == 0) {
            m2[blockIdx.x * 16 + h] = mlM[h];
            l2[blockIdx.x * 16 + h] = mlL[h];
        }
    }
}

// level-1 reduce of block partials: grid (16 heads, 16 groups), block 256.
// Each wave reduces 16 partials; 4 waves LDS-merge -> one group partial.
__global__ __launch_bounds__(256) void attn_red(
    const float* __restrict__ m2, const float* __restrict__ l2,
    const float* __restrict__ acc2,
    float* __restrict__ m3, float* __restrict__ l3, float* __restrict__ acc3) {
    __shared__ float sM[4], sL[4], sA[4][64];
    int h = blockIdx.x, g = blockIdx.y;
    int t = threadIdx.x, w = t >> 6, ld = t & 63;
    int p0 = g * 64 + w * 16;

    float mv[16];
#pragma unroll
    for (int i = 0; i < 16; ++i) mv[i] = m2[(p0 + i) * 16 + h];
    float lm = -1e30f;
#pragma unroll
    for (int i = 0; i < 16; ++i) lm = fmaxf(lm, mv[i]);
    float ll = 0.f, la = 0.f;
#pragma unroll
    for (int i = 0; i < 16; ++i) {
        float e = __expf(mv[i] - lm);
        ll += e * l2[(p0 + i) * 16 + h];
        la += e * acc2[(size_t)(p0 + i) * 64 * 16 + (size_t)h * 64 + ld];
    }
    if (ld == 0) { sM[w] = lm; sL[w] = ll; }
    sA[w][ld] = la;
    __syncthreads();
    if (w == 0) {
        float M = fmaxf(fmaxf(sM[0], sM[1]), fmaxf(sM[2], sM[3]));
        float L = 0.f, a = 0.f;
#pragma unroll
        for (int w4 = 0; w4 < 4; ++w4) {
            float e = __expf(sM[w4] - M);
            L += e * sL[w4];
            a += e * sA[w4][ld];
        }
        acc3[((size_t)g * 16 + h) * 64 + ld] = a;
        if (ld == 0) { m3[g * 16 + h] = M; l3[g * 16 + h] = L; }
    }
}

// Wo GEMV with fused final attention reduce (16 group partials).
// grid (4, 16), block 256. blockIdx.y = head.
__global__ __launch_bounds__(256) void gemv_wo(
    const float* __restrict__ Wo,
    const float* __restrict__ m3, const float* __restrict__ l3,
    const float* __restrict__ acc3, float* __restrict__ part) {
    __shared__ float vals[64];
    int by = blockIdx.y;
    int t = threadIdx.x;
    float M = -1e30f;
#pragma unroll
    for (int g = 0; g < 16; ++g) M = fmaxf(M, m3[g * 16 + by]);
    float L = 0.f;
#pragma unroll
    for (int g = 0; g < 16; ++g) L += __expf(m3[g * 16 + by] - M) * l3[g * 16 + by];
    if (t < 64) {
        float a = 0.f;
#pragma unroll
        for (int g = 0; g < 16; ++g)
            a += __expf(m3[g * 16 + by] - M) * acc3[((size_t)g * 16 + by) * 64 + t];
        vals[t] = a / L;
    }
    __syncthreads();
    int col = blockIdx.x * 256 + t;
    float acc = 0.f;
#pragma unroll 8
    for (int r = 0; r < 64; ++r)
        acc = fmaf(vals[r], Wo[(size_t)(by * 64 + r) * EDIM + col], acc);
    part[(size_t)by * EDIM + col] = acc;
}

// generic GEMV partial: grid (4,16), block 256
__global__ __launch_bounds__(256) void gemv_partial(
    const float* __restrict__ W, const float* __restrict__ xin,
    float* __restrict__ part) {
    int col = blockIdx.x * 256 + threadIdx.x;
    int r0 = blockIdx.y * 64;
    float acc = 0.f;
#pragma unroll 8
    for (int r = 0; r < 64; ++r)
        acc = fmaf(xin[r0 + r], W[(size_t)(r0 + r) * EDIM + col], acc);
    part[(size_t)blockIdx.y * EDIM + col] = acc;
}

// W2 GEMV with fused (bias + sum-partials + ReLU) prologue.
__global__ __launch_bounds__(256) void gemv_w2(
    const float* __restrict__ W2, const float* __restrict__ gp2,
    const float* __restrict__ b1, float* __restrict__ part) {
    __shared__ float vals[64];
    int by = blockIdx.y;
    int t = threadIdx.x;
    if (t < 64) {
        int r = by * 64 + t;
        float v = b1[r];
#pragma unroll
        for (int sl = 0; sl < 16; ++sl) v += gp2[(size_t)sl * EDIM + r];
        vals[t] = fmaxf(v, 0.f);
    }
    __syncthreads();
    int col = blockIdx.x * 256 + t;
    float acc = 0.f;
#pragma unroll 8
    for (int r = 0; r < 64; ++r)
        acc = fmaf(vals[r], W2[(size_t)(by * 64 + r) * EDIM + col], acc);
    part[(size_t)by * EDIM + col] = acc;
}

// 1 block 1024: r = resid + bias + sum partials; out = LN(r)*g + b
__global__ __launch_bounds__(1024) void combine_ln(
    const float* __restrict__ part, const float* __restrict__ bias,
    const float* __restrict__ resid, const float* __restrict__ g,
    const float* __restrict__ b, float* __restrict__ out) {
    __shared__ float lds[32];
    int t = threadIdx.x;
    float v = bias[t];
#pragma unroll
    for (int sl = 0; sl < 16; ++sl) v += part[(size_t)sl * EDIM + t];
    float r = resid[t] + v;
    float mean = blockSum1024(r, lds) * (1.f / 1024.f);
    float d = r - mean;
    float var = blockSum1024(d * d, lds) * (1.f / 1024.f);
    out[t] = d * rsqrtf(var + 1e-6f) * g[t] + b[t];
}

// ---------------- launch ----------------
extern "C" void kernel_launch(void* const* d_in, const int* in_sizes, int n_in,
                              void* d_out, int out_size, void* d_ws, size_t ws_size,
                              hipStream_t stream) {
    const float* x     = (const float*)d_in[0];
    const float* cache = (const float*)d_in[1];
    const float* Wv    = (const float*)d_in[2];
    const float* bv    = (const float*)d_in[3];
    const float* Wq    = (const float*)d_in[4];
    const float* bq    = (const float*)d_in[5];
    const float* Wk    = (const float*)d_in[6];
    const float* bk    = (const float*)d_in[7];
    const float* Wo    = (const float*)d_in[8];
    const float* bo    = (const float*)d_in[9];
    const float* W1    = (const float*)d_in[10];
    const float* b1    = (const float*)d_in[11];
    const float* W2    = (const float*)d_in[12];
    const float* b2    = (const float*)d_in[13];
    const float* ln1s  = (const float*)d_in[14];
    const float* ln1b  = (const float*)d_in[15];
    const float* ln2s  = (const float*)d_in[16];
    const float* ln2b  = (const float*)d_in[17];

    float* out = (float*)d_out;
    float* nv = out + 1024;
    float* nk = out + 1024 + (size_t)SLEN * EDIM;

    float* w      = (float*)d_ws;
    float* qs     = w;                          // 1024
    float* ki     = qs + 1024;                  // 1024
    float* vi     = ki + 1024;                  // 1024
    float* qkvp   = vi + 1024;                  // 48*1024
    float* m2     = qkvp + 48 * 1024;           // NB*16
    float* l2     = m2 + (size_t)NB * 16;       // NB*16
    float* acc2   = l2 + (size_t)NB * 16;       // NB*1024
    float* m3     = acc2 + (size_t)NB * 1024;   // 256
    float* l3     = m3 + 256;                   // 256
    float* acc3   = l3 + 256;                   // 16*1024
    float* h1     = acc3 + 16 * 1024;           // 1024
    float* gp1    = h1 + 1024;                  // 16*1024
    float* gp2    = gp1 + 16 * 1024;            // 16*1024
    float* gp3    = gp2 + 16 * 1024;            // 16*1024

    qkv_partial<<<dim3(12, 16), 256, 0, stream>>>(Wq, Wk, Wv, x, qkvp);
    qkv_combine<<<3, 1024, 0, stream>>>(qkvp, bq, bk, bv, qs, ki, vi);
    attn_main<<<NB, 512, 0, stream>>>(cache, qs, ki, vi, nv, nk, m2, l2, acc2);
    attn_red<<<dim3(16, 16), 256, 0, stream>>>(m2, l2, acc2, m3, l3, acc3);
    gemv_wo<<<dim3(4, 16), 256, 0, stream>>>(Wo, m3, l3, acc3, gp1);
    combine_ln<<<1, 1024, 0, stream>>>(gp1, bo, x, ln1s, ln1b, h1);
    gemv_partial<<<dim3(4, 16), 256, 0, stream>>>(W1, h1, gp2);
    gemv_w2<<<dim3(4, 16), 256, 0, stream>>>(W2, gp2, b1, gp3);
    combine_ln<<<1, 1024, 0, stream>>>(gp3, b2, h1, ln2s, ln2b, out);
}

// Round 6
// 62.441 us; speedup vs baseline: 1.8902x; 1.0064x over previous
//
#include <hip/hip_runtime.h>
#include <hip/hip_bf16.h>

#define SLEN 8192
#define EDIM 1024
#define NB   1024   // attention blocks; 8 positions per block (one per wave)

typedef float f4 __attribute__((ext_vector_type(4)));

// ---------------- helpers ----------------

__device__ inline float waveReduceSum64(float v) {
#pragma unroll
    for (int off = 32; off; off >>= 1) v += __shfl_xor(v, off);
    return v;
}

__device__ inline float blockSum1024(float v, float* lds) {
    v = waveReduceSum64(v);
    int w = threadIdx.x >> 6, ln = threadIdx.x & 63;
    __syncthreads();
    if (ln == 0) lds[w] = v;
    __syncthreads();
    float s = (ln < 16) ? lds[ln] : 0.f;
#pragma unroll
    for (int off = 8; off; off >>= 1) s += __shfl_xor(s, off);
    s = __shfl(s, 0);
    return s;
}

// ---------------- QKV GEMV (split-K partials) ----------------
// grid (12, 16), block 256
__global__ __launch_bounds__(256) void qkv_partial(
    const float* __restrict__ Wq, const float* __restrict__ Wk,
    const float* __restrict__ Wv, const float* __restrict__ x,
    float* __restrict__ part) {
    int cg = blockIdx.x;
    int m = cg >> 2;
    const float* W = (m == 0) ? Wq : ((m == 1) ? Wk : Wv);
    int col = (cg & 3) * 256 + threadIdx.x;
    int r0 = blockIdx.y * 64;
    float acc = 0.f;
#pragma unroll 8
    for (int r = 0; r < 64; ++r)
        acc = fmaf(x[r0 + r], W[(r0 + r) * EDIM + col], acc);
    part[((size_t)m * 16 + blockIdx.y) * EDIM + col] = acc;
}

// grid 3, block 1024
__global__ __launch_bounds__(1024) void qkv_combine(
    const float* __restrict__ part,
    const float* __restrict__ bq, const float* __restrict__ bk,
    const float* __restrict__ bv,
    float* __restrict__ qs, float* __restrict__ ki, float* __restrict__ vi) {
    int m = blockIdx.x, t = threadIdx.x;
    float v = 0.f;
#pragma unroll
    for (int sl = 0; sl < 16; ++sl) v += part[((size_t)m * 16 + sl) * EDIM + t];
    if (m == 0) qs[t] = (v + bq[t]) * 0.125f;   // pre-scale q by 1/sqrt(64)
    else if (m == 1) ki[t] = v + bk[t];
    else vi[t] = v + bv[t];
}

// ---------------- fused cache-shift + attention with block merge ----------------
// grid NB, block 512 (8 waves). Wave w owns position s = blockIdx.x*8 + w.
__global__ __launch_bounds__(512) void attn_main(
    const float* __restrict__ cache,   // [2, S, 1024]
    const float* __restrict__ qs,      // q/8 [1024]
    const float* __restrict__ ki, const float* __restrict__ vi,
    float* __restrict__ nv, float* __restrict__ nk,
    float* __restrict__ m2, float* __restrict__ l2, float* __restrict__ acc2) {
    __shared__ float sm[8][16];        // per-wave per-head scores
    __shared__ float mlM[16], mlL[16];
    __shared__ float sacc[8][16][64];  // 32 KB weighted V
    int tid = threadIdx.x;
    int w = tid >> 6, ld = tid & 63;
    int s = blockIdx.x * 8 + w;

    const float* vsrc;
    const float* ksrc;
    bool last = (s >= SLEN - 1);
    if (!last) {
        vsrc = cache + (size_t)(s + 1) * EDIM;
        ksrc = cache + (size_t)(SLEN + s + 1) * EDIM;
    } else {
        vsrc = vi; ksrc = ki;
    }

    // issue ALL streaming loads first (8 outstanding 16B loads/thread),
    // non-temporal: single-use stream, keep L2 for weights.
    f4 vv[4], kv[4];
    if (!last) {
#pragma unroll
        for (int it = 0; it < 4; ++it)
            vv[it] = __builtin_nontemporal_load((const f4*)(vsrc + it * 256 + ld * 4));
#pragma unroll
        for (int it = 0; it < 4; ++it)
            kv[it] = __builtin_nontemporal_load((const f4*)(ksrc + it * 256 + ld * 4));
    } else {
#pragma unroll
        for (int it = 0; it < 4; ++it)
            vv[it] = *(const f4*)(vsrc + it * 256 + ld * 4);
#pragma unroll
        for (int it = 0; it < 4; ++it)
            kv[it] = *(const f4*)(ksrc + it * 256 + ld * 4);
    }

    bool nz = false;
#pragma unroll
    for (int it = 0; it < 4; ++it) {
        __builtin_nontemporal_store(vv[it], (f4*)(nv + (size_t)s * EDIM + it * 256 + ld * 4));
        nz = nz || (vv[it].x != 0.f) || (vv[it].y != 0.f) ||
             (vv[it].z != 0.f) || (vv[it].w != 0.f);
    }
    float sc[4];
#pragma unroll
    for (int it = 0; it < 4; ++it) {
        f4 q4 = *(const f4*)(qs + it * 256 + ld * 4);
        __builtin_nontemporal_store(kv[it], (f4*)(nk + (size_t)s * EDIM + it * 256 + ld * 4));
        float d = q4.x * kv[it].x + q4.y * kv[it].y + q4.z * kv[it].z + q4.w * kv[it].w;
        d += __shfl_xor(d, 1);
        d += __shfl_xor(d, 2);
        d += __shfl_xor(d, 4);
        d += __shfl_xor(d, 8);
        sc[it] = d;    // score for head it*4 + (ld>>4)
    }
    if (__ballot(nz) == 0ull) {
#pragma unroll
        for (int it = 0; it < 4; ++it) sc[it] = -1e30f;
    }
    if ((ld & 15) == 0) {
#pragma unroll
        for (int it = 0; it < 4; ++it) sm[w][it * 4 + (ld >> 4)] = sc[it];
    }
    __syncthreads();

#pragma unroll
    for (int it = 0; it < 4; ++it) {
        int h = it * 4 + (ld >> 4);
        float M = sm[0][h];
#pragma unroll
        for (int ww = 1; ww < 8; ++ww) M = fmaxf(M, sm[ww][h]);
        float L = 0.f;
#pragma unroll
        for (int ww = 0; ww < 8; ++ww) L += __expf(sm[ww][h] - M);
        if ((ld & 15) == 1) { mlM[h] = M; mlL[h] = L; }
        float wg = __expf(sc[it] - M);
        *(f4*)&sacc[w][h][(ld & 15) * 4] =
            (f4){wg * vv[it].x, wg * vv[it].y, wg * vv[it].z, wg * vv[it].w};
    }
    __syncthreads();

#pragma unroll
    for (int j = 0; j < 2; ++j) {
        int h = 2 * w + j;
        float a = 0.f;
#pragma unroll
        for (int ww = 0; ww < 8; ++ww) a += sacc[ww][h][ld];
        acc2[((size_t)blockIdx.x * 16 + h) * 64 + ld] = a;
        if (ld == 0) {
            m2[blockIdx.x * 16 + h] = mlM[h];
            l2[blockIdx.x * 16 + h] = mlL[h];
        }
    }
}

// level-1 reduce of block partials: grid (16 heads, 16 groups), block 256.
__global__ __launch_bounds__(256) void attn_red(
    const float* __restrict__ m2, const float* __restrict__ l2,
    const float* __restrict__ acc2,
    float* __restrict__ m3, float* __restrict__ l3, float* __restrict__ acc3) {
    __shared__ float sM[4], sL[4], sA[4][64];
    int h = blockIdx.x, g = blockIdx.y;
    int t = threadIdx.x, w = t >> 6, ld = t & 63;
    int p0 = g * 64 + w * 16;

    float mv[16];
#pragma unroll
    for (int i = 0; i < 16; ++i) mv[i] = m2[(p0 + i) * 16 + h];
    float lm = -1e30f;
#pragma unroll
    for (int i = 0; i < 16; ++i) lm = fmaxf(lm, mv[i]);
    float ll = 0.f, la = 0.f;
#pragma unroll
    for (int i = 0; i < 16; ++i) {
        float e = __expf(mv[i] - lm);
        ll += e * l2[(p0 + i) * 16 + h];
        la += e * acc2[(size_t)(p0 + i) * 64 * 16 + (size_t)h * 64 + ld];
    }
    if (ld == 0) { sM[w] = lm; sL[w] = ll; }
    sA[w][ld] = la;
    __syncthreads();
    if (w == 0) {
        float M = fmaxf(fmaxf(sM[0], sM[1]), fmaxf(sM[2], sM[3]));
        float L = 0.f, a = 0.f;
#pragma unroll
        for (int w4 = 0; w4 < 4; ++w4) {
            float e = __expf(sM[w4] - M);
            L += e * sL[w4];
            a += e * sA[w4][ld];
        }
        acc3[((size_t)g * 16 + h) * 64 + ld] = a;
        if (ld == 0) { m3[g * 16 + h] = M; l3[g * 16 + h] = L; }
    }
}

// Wo GEMV with fused final attention reduce (16 group partials).
// grid (4, 16), block 256. blockIdx.y = head.
__global__ __launch_bounds__(256) void gemv_wo(
    const float* __restrict__ Wo,
    const float* __restrict__ m3, const float* __restrict__ l3,
    const float* __restrict__ acc3, float* __restrict__ part) {
    __shared__ float vals[64];
    int by = blockIdx.y;
    int t = threadIdx.x;
    float M = -1e30f;
#pragma unroll
    for (int g = 0; g < 16; ++g) M = fmaxf(M, m3[g * 16 + by]);
    float L = 0.f;
#pragma unroll
    for (int g = 0; g < 16; ++g) L += __expf(m3[g * 16 + by] - M) * l3[g * 16 + by];
    if (t < 64) {
        float a = 0.f;
#pragma unroll
        for (int g = 0; g < 16; ++g)
            a += __expf(m3[g * 16 + by] - M) * acc3[((size_t)g * 16 + by) * 64 + t];
        vals[t] = a / L;
    }
    __syncthreads();
    int col = blockIdx.x * 256 + t;
    float acc = 0.f;
#pragma unroll 8
    for (int r = 0; r < 64; ++r)
        acc = fmaf(vals[r], Wo[(size_t)(by * 64 + r) * EDIM + col], acc);
    part[(size_t)by * EDIM + col] = acc;
}

// generic GEMV partial: grid (4,16), block 256
__global__ __launch_bounds__(256) void gemv_partial(
    const float* __restrict__ W, const float* __restrict__ xin,
    float* __restrict__ part) {
    int col = blockIdx.x * 256 + threadIdx.x;
    int r0 = blockIdx.y * 64;
    float acc = 0.f;
#pragma unroll 8
    for (int r = 0; r < 64; ++r)
        acc = fmaf(xin[r0 + r], W[(size_t)(r0 + r) * EDIM + col], acc);
    part[(size_t)blockIdx.y * EDIM + col] = acc;
}

// W2 GEMV with fused (bias + sum-partials + ReLU) prologue.
__global__ __launch_bounds__(256) void gemv_w2(
    const float* __restrict__ W2, const float* __restrict__ gp2,
    const float* __restrict__ b1, float* __restrict__ part) {
    __shared__ float vals[64];
    int by = blockIdx.y;
    int t = threadIdx.x;
    if (t < 64) {
        int r = by * 64 + t;
        float v = b1[r];
#pragma unroll
        for (int sl = 0; sl < 16; ++sl) v += gp2[(size_t)sl * EDIM + r];
        vals[t] = fmaxf(v, 0.f);
    }
    __syncthreads();
    int col = blockIdx.x * 256 + t;
    float acc = 0.f;
#pragma unroll 8
    for (int r = 0; r < 64; ++r)
        acc = fmaf(vals[r], W2[(size_t)(by * 64 + r) * EDIM + col], acc);
    part[(size_t)by * EDIM + col] = acc;
}

// 1 block 1024: r = resid + bias + sum partials; out = LN(r)*g + b
__global__ __launch_bounds__(1024) void combine_ln(
    const float* __restrict__ part, const float* __restrict__ bias,
    const float* __restrict__ resid, const float* __restrict__ g,
    const float* __restrict__ b, float* __restrict__ out) {
    __shared__ float lds[32];
    int t = threadIdx.x;
    float v = bias[t];
#pragma unroll
    for (int sl = 0; sl < 16; ++sl) v += part[(size_t)sl * EDIM + t];
    float r = resid[t] + v;
    float mean = blockSum1024(r, lds) * (1.f / 1024.f);
    float d = r - mean;
    float var = blockSum1024(d * d, lds) * (1.f / 1024.f);
    out[t] = d * rsqrtf(var + 1e-6f) * g[t] + b[t];
}

// ---------------- launch ----------------
extern "C" void kernel_launch(void* const* d_in, const int* in_sizes, int n_in,
                              void* d_out, int out_size, void* d_ws, size_t ws_size,
                              hipStream_t stream) {
    const float* x     = (const float*)d_in[0];
    const float* cache = (const float*)d_in[1];
    const float* Wv    = (const float*)d_in[2];
    const float* bv    = (const float*)d_in[3];
    const float* Wq    = (const float*)d_in[4];
    const float* bq    = (const float*)d_in[5];
    const float* Wk    = (const float*)d_in[6];
    const float* bk    = (const float*)d_in[7];
    const float* Wo    = (const float*)d_in[8];
    const float* bo    = (const float*)d_in[9];
    const float* W1    = (const float*)d_in[10];
    const float* b1    = (const float*)d_in[11];
    const float* W2    = (const float*)d_in[12];
    const float* b2    = (const float*)d_in[13];
    const float* ln1s  = (const float*)d_in[14];
    const float* ln1b  = (const float*)d_in[15];
    const float* ln2s  = (const float*)d_in[16];
    const float* ln2b  = (const float*)d_in[17];

    float* out = (float*)d_out;
    float* nv = out + 1024;
    float* nk = out + 1024 + (size_t)SLEN * EDIM;

    float* w      = (float*)d_ws;
    float* qs     = w;                          // 1024
    float* ki     = qs + 1024;                  // 1024
    float* vi     = ki + 1024;                  // 1024
    float* qkvp   = vi + 1024;                  // 48*1024
    float* m2     = qkvp + 48 * 1024;           // NB*16
    float* l2     = m2 + (size_t)NB * 16;       // NB*16
    float* acc2   = l2 + (size_t)NB * 16;       // NB*1024
    float* m3     = acc2 + (size_t)NB * 1024;   // 256
    float* l3     = m3 + 256;                   // 256
    float* acc3   = l3 + 256;                   // 16*1024
    float* h1     = acc3 + 16 * 1024;           // 1024
    float* gp1    = h1 + 1024;                  // 16*1024
    float* gp2    = gp1 + 16 * 1024;            // 16*1024
    float* gp3    = gp2 + 16 * 1024;            // 16*1024

    qkv_partial<<<dim3(12, 16), 256, 0, stream>>>(Wq, Wk, Wv, x, qkvp);
    qkv_combine<<<3, 1024, 0, stream>>>(qkvp, bq, bk, bv, qs, ki, vi);
    attn_main<<<NB, 512, 0, stream>>>(cache, qs, ki, vi, nv, nk, m2, l2, acc2);
    attn_red<<<dim3(16, 16), 256, 0, stream>>>(m2, l2, acc2, m3, l3, acc3);
    gemv_wo<<<dim3(4, 16), 256, 0, stream>>>(Wo, m3, l3, acc3, gp1);
    combine_ln<<<1, 1024, 0, stream>>>(gp1, bo, x, ln1s, ln1b, h1);
    gemv_partial<<<dim3(4, 16), 256, 0, stream>>>(W1, h1, gp2);
    gemv_w2<<<dim3(4, 16), 256, 0, stream>>>(W2, gp2, b1, gp3);
    combine_ln<<<1, 1024, 0, stream>>>(gp3, b2, h1, ln2s, ln2b, out);
}

// Round 7
// 61.134 us; speedup vs baseline: 1.9306x; 1.0214x over previous
//
#include <hip/hip_runtime.h>
#include <hip/hip_bf16.h>

#define SLEN 8192
#define EDIM 1024
#define NB   1024   // attention blocks; 8 positions per block (one per wave)

typedef float f4 __attribute__((ext_vector_type(4)));

// ---------------- helpers ----------------

// block-wide (256 thr) sum of (x, x2); result broadcast
__device__ inline float2 blockSum256_2(float2 v, float2* lds) {
#pragma unroll
    for (int off = 32; off; off >>= 1) {
        v.x += __shfl_xor(v.x, off);
        v.y += __shfl_xor(v.y, off);
    }
    int w = threadIdx.x >> 6, ln = threadIdx.x & 63;
    __syncthreads();
    if (ln == 0) lds[w] = v;
    __syncthreads();
    float2 s;
    s.x = lds[0].x + lds[1].x + lds[2].x + lds[3].x;
    s.y = lds[0].y + lds[1].y + lds[2].y + lds[3].y;
    return s;
}

// block-wide (1024 thr) sum of (x, x2); result broadcast
__device__ inline float2 blockSum1024_2(float2 v, float2* lds) {
#pragma unroll
    for (int off = 32; off; off >>= 1) {
        v.x += __shfl_xor(v.x, off);
        v.y += __shfl_xor(v.y, off);
    }
    int w = threadIdx.x >> 6, ln = threadIdx.x & 63;
    __syncthreads();
    if (ln == 0) lds[w] = v;
    __syncthreads();
    float2 s = {0.f, 0.f};
#pragma unroll
    for (int i = 0; i < 16; ++i) { s.x += lds[i].x; s.y += lds[i].y; }
    return s;
}

// ---------------- QKV GEMV (split-K partials) ----------------
// grid (12, 16), block 256
__global__ __launch_bounds__(256) void qkv_partial(
    const float* __restrict__ Wq, const float* __restrict__ Wk,
    const float* __restrict__ Wv, const float* __restrict__ x,
    float* __restrict__ part) {
    int cg = blockIdx.x;
    int m = cg >> 2;
    const float* W = (m == 0) ? Wq : ((m == 1) ? Wk : Wv);
    int col = (cg & 3) * 256 + threadIdx.x;
    int r0 = blockIdx.y * 64;
    float acc = 0.f;
#pragma unroll 8
    for (int r = 0; r < 64; ++r)
        acc = fmaf(x[r0 + r], W[(r0 + r) * EDIM + col], acc);
    part[((size_t)m * 16 + blockIdx.y) * EDIM + col] = acc;
}

// grid 3, block 1024
__global__ __launch_bounds__(1024) void qkv_combine(
    const float* __restrict__ part,
    const float* __restrict__ bq, const float* __restrict__ bk,
    const float* __restrict__ bv,
    float* __restrict__ qs, float* __restrict__ ki, float* __restrict__ vi) {
    int m = blockIdx.x, t = threadIdx.x;
    float v = 0.f;
#pragma unroll
    for (int sl = 0; sl < 16; ++sl) v += part[((size_t)m * 16 + sl) * EDIM + t];
    if (m == 0) qs[t] = (v + bq[t]) * 0.125f;   // pre-scale q by 1/sqrt(64)
    else if (m == 1) ki[t] = v + bk[t];
    else vi[t] = v + bv[t];
}

// ---------------- fused cache-shift + attention with block merge ----------------
// grid NB, block 512 (8 waves). Wave w owns position s = blockIdx.x*8 + w.
// VALU-diet version: bit-OR nz test; per-head M/L computed once by wave 0.
__global__ __launch_bounds__(512) void attn_main(
    const float* __restrict__ cache,   // [2, S, 1024]
    const float* __restrict__ qs,      // q/8 [1024]
    const float* __restrict__ ki, const float* __restrict__ vi,
    float* __restrict__ nv, float* __restrict__ nk,
    float* __restrict__ m2, float* __restrict__ l2, float* __restrict__ acc2) {
    __shared__ float sm[8][16];        // per-wave per-head scores
    __shared__ float mlM[16], mlL[16];
    __shared__ float sacc[8][16][64];  // 32 KB weighted V
    int tid = threadIdx.x;
    int w = tid >> 6, ld = tid & 63;
    int s = blockIdx.x * 8 + w;

    bool last = (s >= SLEN - 1);
    const float* vsrc = last ? vi : cache + (size_t)(s + 1) * EDIM;
    const float* ksrc = last ? ki : cache + (size_t)(SLEN + s + 1) * EDIM;

    // all streaming loads issued up front, non-temporal
    f4 vv[4], kv[4], q4[4];
#pragma unroll
    for (int it = 0; it < 4; ++it)
        vv[it] = __builtin_nontemporal_load((const f4*)(vsrc + it * 256 + ld * 4));
#pragma unroll
    for (int it = 0; it < 4; ++it)
        kv[it] = __builtin_nontemporal_load((const f4*)(ksrc + it * 256 + ld * 4));
#pragma unroll
    for (int it = 0; it < 4; ++it)
        q4[it] = *(const f4*)(qs + it * 256 + ld * 4);

    // V: store to new cache + bitwise nz
    unsigned nzb = 0u;
#pragma unroll
    for (int it = 0; it < 4; ++it) {
        __builtin_nontemporal_store(vv[it], (f4*)(nv + (size_t)s * EDIM + it * 256 + ld * 4));
        nzb |= __float_as_uint(vv[it].x) | __float_as_uint(vv[it].y) |
               __float_as_uint(vv[it].z) | __float_as_uint(vv[it].w);
    }
    // K: store + per-head dot (16-lane-group shfl reduce)
    float sc[4];
#pragma unroll
    for (int it = 0; it < 4; ++it) {
        __builtin_nontemporal_store(kv[it], (f4*)(nk + (size_t)s * EDIM + it * 256 + ld * 4));
        float d = q4[it].x * kv[it].x + q4[it].y * kv[it].y +
                  q4[it].z * kv[it].z + q4[it].w * kv[it].w;
        d += __shfl_xor(d, 1);
        d += __shfl_xor(d, 2);
        d += __shfl_xor(d, 4);
        d += __shfl_xor(d, 8);
        sc[it] = d;    // score for head it*4 + (ld>>4)
    }
    if (__ballot(nzb != 0u) == 0ull) {
#pragma unroll
        for (int it = 0; it < 4; ++it) sc[it] = -1e30f;
    }
    if ((ld & 15) == 0) {
#pragma unroll
        for (int it = 0; it < 4; ++it) sm[w][it * 4 + (ld >> 4)] = sc[it];
    }
    __syncthreads();

    // wave 0, lanes 0..15: per-head block max & partition sum (computed ONCE)
    if (tid < 16) {
        float M = sm[0][tid];
#pragma unroll
        for (int ww = 1; ww < 8; ++ww) M = fmaxf(M, sm[ww][tid]);
        float L = 0.f;
#pragma unroll
        for (int ww = 0; ww < 8; ++ww) L += __expf(sm[ww][tid] - M);
        mlM[tid] = M; mlL[tid] = L;
    }
    __syncthreads();

    // each thread: own weight only (4 exps), write weighted V to LDS
#pragma unroll
    for (int it = 0; it < 4; ++it) {
        int h = it * 4 + (ld >> 4);
        float wg = __expf(sc[it] - mlM[h]);
        *(f4*)&sacc[w][h][(ld & 15) * 4] =
            (f4){wg * vv[it].x, wg * vv[it].y, wg * vv[it].z, wg * vv[it].w};
    }
    __syncthreads();

    // wave w reduces heads 2w, 2w+1 across the 8 waves; write block partial
#pragma unroll
    for (int j = 0; j < 2; ++j) {
        int h = 2 * w + j;
        float a = 0.f;
#pragma unroll
        for (int ww = 0; ww < 8; ++ww) a += sacc[ww][h][ld];
        acc2[((size_t)blockIdx.x * 16 + h) * 64 + ld] = a;
        if (ld == 0) {
            m2[blockIdx.x * 16 + h] = mlM[h];
            l2[blockIdx.x * 16 + h] = mlL[h];
        }
    }
}

// level-1 reduce of block partials: grid (16 heads, 16 groups), block 256.
__global__ __launch_bounds__(256) void attn_red(
    const float* __restrict__ m2, const float* __restrict__ l2,
    const float* __restrict__ acc2,
    float* __restrict__ m3, float* __restrict__ l3, float* __restrict__ acc3) {
    __shared__ float sM[4], sL[4], sA[4][64];
    int h = blockIdx.x, g = blockIdx.y;
    int t = threadIdx.x, w = t >> 6, ld = t & 63;
    int p0 = g * 64 + w * 16;

    float mv[16];
#pragma unroll
    for (int i = 0; i < 16; ++i) mv[i] = m2[(p0 + i) * 16 + h];
    float lm = -1e30f;
#pragma unroll
    for (int i = 0; i < 16; ++i) lm = fmaxf(lm, mv[i]);
    float ll = 0.f, la = 0.f;
#pragma unroll
    for (int i = 0; i < 16; ++i) {
        float e = __expf(mv[i] - lm);
        ll += e * l2[(p0 + i) * 16 + h];
        la += e * acc2[(size_t)(p0 + i) * 1024 + (size_t)h * 64 + ld];
    }
    if (ld == 0) { sM[w] = lm; sL[w] = ll; }
    sA[w][ld] = la;
    __syncthreads();
    if (w == 0) {
        float M = fmaxf(fmaxf(sM[0], sM[1]), fmaxf(sM[2], sM[3]));
        float L = 0.f, a = 0.f;
#pragma unroll
        for (int w4 = 0; w4 < 4; ++w4) {
            float e = __expf(sM[w4] - M);
            L += e * sL[w4];
            a += e * sA[w4][ld];
        }
        acc3[((size_t)g * 16 + h) * 64 + ld] = a;
        if (ld == 0) { m3[g * 16 + h] = M; l3[g * 16 + h] = L; }
    }
}

// Wo GEMV with fused final attention reduce (16 group partials).
// grid (4, 16), block 256. blockIdx.y = head.
__global__ __launch_bounds__(256) void gemv_wo(
    const float* __restrict__ Wo,
    const float* __restrict__ m3, const float* __restrict__ l3,
    const float* __restrict__ acc3, float* __restrict__ part) {
    __shared__ float vals[64];
    int by = blockIdx.y;
    int t = threadIdx.x;
    float M = -1e30f;
#pragma unroll
    for (int g = 0; g < 16; ++g) M = fmaxf(M, m3[g * 16 + by]);
    float L = 0.f;
#pragma unroll
    for (int g = 0; g < 16; ++g) L += __expf(m3[g * 16 + by] - M) * l3[g * 16 + by];
    if (t < 64) {
        float a = 0.f;
#pragma unroll
        for (int g = 0; g < 16; ++g)
            a += __expf(m3[g * 16 + by] - M) * acc3[((size_t)g * 16 + by) * 64 + t];
        vals[t] = a / L;
    }
    __syncthreads();
    int col = blockIdx.x * 256 + t;
    float acc = 0.f;
#pragma unroll 8
    for (int r = 0; r < 64; ++r)
        acc = fmaf(vals[r], Wo[(size_t)(by * 64 + r) * EDIM + col], acc);
    part[(size_t)by * EDIM + col] = acc;
}

// W1 GEMV with fused residual+LN1 prologue.
// grid (4,16), block 256. Each block recomputes r = x + bo + sum(gp1) and its
// LN stats (one-pass E[x^2]-m^2), then GEMVs its 64-row slice of W1.
// blockIdx.x==0 blocks also persist h1 (needed as residual for final LN).
__global__ __launch_bounds__(256) void gemv_w1(
    const float* __restrict__ W1, const float* __restrict__ gp1,
    const float* __restrict__ bo, const float* __restrict__ x,
    const float* __restrict__ ln1s, const float* __restrict__ ln1b,
    float* __restrict__ h1, float* __restrict__ part) {
    __shared__ float r_l[1024];
    __shared__ float2 red[4];
    __shared__ float vals[64];
    int t = threadIdx.x;
    float2 ss = {0.f, 0.f};
#pragma unroll
    for (int j = 0; j < 4; ++j) {
        int i = t + 256 * j;
        float v = x[i] + bo[i];
#pragma unroll
        for (int sl = 0; sl < 16; ++sl) v += gp1[(size_t)sl * EDIM + i];
        r_l[i] = v;
        ss.x += v; ss.y += v * v;
    }
    float2 s = blockSum256_2(ss, red);
    float mean = s.x * (1.f / 1024.f);
    float var = s.y * (1.f / 1024.f) - mean * mean;
    float rstd = rsqrtf(var + 1e-6f);
    int by = blockIdx.y;
    if (t < 64) {
        int row = by * 64 + t;
        float hv = (r_l[row] - mean) * rstd * ln1s[row] + ln1b[row];
        vals[t] = hv;
        if (blockIdx.x == 0) h1[row] = hv;
    }
    __syncthreads();
    int col = blockIdx.x * 256 + t;
    float acc = 0.f;
#pragma unroll 8
    for (int r = 0; r < 64; ++r)
        acc = fmaf(vals[r], W1[(size_t)(by * 64 + r) * EDIM + col], acc);
    part[(size_t)by * EDIM + col] = acc;
}

// W2 GEMV with fused (bias + sum-partials + ReLU) prologue.
__global__ __launch_bounds__(256) void gemv_w2(
    const float* __restrict__ W2, const float* __restrict__ gp2,
    const float* __restrict__ b1, float* __restrict__ part) {
    __shared__ float vals[64];
    int by = blockIdx.y;
    int t = threadIdx.x;
    if (t < 64) {
        int r = by * 64 + t;
        float v = b1[r];
#pragma unroll
        for (int sl = 0; sl < 16; ++sl) v += gp2[(size_t)sl * EDIM + r];
        vals[t] = fmaxf(v, 0.f);
    }
    __syncthreads();
    int col = blockIdx.x * 256 + t;
    float acc = 0.f;
#pragma unroll 8
    for (int r = 0; r < 64; ++r)
        acc = fmaf(vals[r], W2[(size_t)(by * 64 + r) * EDIM + col], acc);
    part[(size_t)by * EDIM + col] = acc;
}

// final LN: 1 block 1024. r = h1 + b2 + sum partials; out = LN(r)*g + b
__global__ __launch_bounds__(1024) void combine_ln(
    const float* __restrict__ part, const float* __restrict__ bias,
    const float* __restrict__ resid, const float* __restrict__ g,
    const float* __restrict__ b, float* __restrict__ out) {
    __shared__ float2 lds[16];
    int t = threadIdx.x;
    float v = bias[t];
#pragma unroll
    for (int sl = 0; sl < 16; ++sl) v += part[(size_t)sl * EDIM + t];
    float r = resid[t] + v;
    float2 s = blockSum1024_2((float2){r, r * r}, lds);
    float mean = s.x * (1.f / 1024.f);
    float var = s.y * (1.f / 1024.f) - mean * mean;
    out[t] = (r - mean) * rsqrtf(var + 1e-6f) * g[t] + b[t];
}

// ---------------- launch ----------------
extern "C" void kernel_launch(void* const* d_in, const int* in_sizes, int n_in,
                              void* d_out, int out_size, void* d_ws, size_t ws_size,
                              hipStream_t stream) {
    const float* x     = (const float*)d_in[0];
    const float* cache = (const float*)d_in[1];
    const float* Wv    = (const float*)d_in[2];
    const float* bv    = (const float*)d_in[3];
    const float* Wq    = (const float*)d_in[4];
    const float* bq    = (const float*)d_in[5];
    const float* Wk    = (const float*)d_in[6];
    const float* bk    = (const float*)d_in[7];
    const float* Wo    = (const float*)d_in[8];
    const float* bo    = (const float*)d_in[9];
    const float* W1    = (const float*)d_in[10];
    const float* b1    = (const float*)d_in[11];
    const float* W2    = (const float*)d_in[12];
    const float* b2    = (const float*)d_in[13];
    const float* ln1s  = (const float*)d_in[14];
    const float* ln1b  = (const float*)d_in[15];
    const float* ln2s  = (const float*)d_in[16];
    const float* ln2b  = (const float*)d_in[17];

    float* out = (float*)d_out;
    float* nv = out + 1024;
    float* nk = out + 1024 + (size_t)SLEN * EDIM;

    float* w      = (float*)d_ws;
    float* qs     = w;                          // 1024
    float* ki     = qs + 1024;                  // 1024
    float* vi     = ki + 1024;                  // 1024
    float* qkvp   = vi + 1024;                  // 48*1024
    float* m2     = qkvp + 48 * 1024;           // NB*16
    float* l2     = m2 + (size_t)NB * 16;       // NB*16
    float* acc2   = l2 + (size_t)NB * 16;       // NB*1024
    float* m3     = acc2 + (size_t)NB * 1024;   // 256
    float* l3     = m3 + 256;                   // 256
    float* acc3   = l3 + 256;                   // 16*1024
    float* h1     = acc3 + 16 * 1024;           // 1024
    float* gp1    = h1 + 1024;                  // 16*1024
    float* gp2    = gp1 + 16 * 1024;            // 16*1024
    float* gp3    = gp2 + 16 * 1024;            // 16*1024

    qkv_partial<<<dim3(12, 16), 256, 0, stream>>>(Wq, Wk, Wv, x, qkvp);
    qkv_combine<<<3, 1024, 0, stream>>>(qkvp, bq, bk, bv, qs, ki, vi);
    attn_main<<<NB, 512, 0, stream>>>(cache, qs, ki, vi, nv, nk, m2, l2, acc2);
    attn_red<<<dim3(16, 16), 256, 0, stream>>>(m2, l2, acc2, m3, l3, acc3);
    gemv_wo<<<dim3(4, 16), 256, 0, stream>>>(Wo, m3, l3, acc3, gp1);
    gemv_w1<<<dim3(4, 16), 256, 0, stream>>>(W1, gp1, bo, x, ln1s, ln1b, h1, gp2);
    gemv_w2<<<dim3(4, 16), 256, 0, stream>>>(W2, gp2, b1, gp3);
    combine_ln<<<1, 1024, 0, stream>>>(gp3, b2, h1, ln2s, ln2b, out);
}